// Round 8
// baseline (162.167 us; speedup 1.0000x reference)
//
#include <hip/hip_runtime.h>
#include <hip/hip_bf16.h>
#include <stdint.h>

typedef __attribute__((ext_vector_type(8)))  short short8;
typedef __attribute__((ext_vector_type(16))) float f32x16;

#define NROWS 500000
#define NCHUNK 7813          // ceil(500000/64); chunk 7812: nt=0 full, nt=1 guarded
#define NBLK 256
#define NTHR 512
#define NWAVE_TOT (NBLK * 8)

// swap bits 2<->3 (involution); aligns MFMA D-layout (row=(reg&3)+8(reg>>2)+4hi)
// with B-frag k-layout (k = 16kt + 8hi + j). HW-verified in r6 (absmax 0.047).
#define SW(v) ((((v) & ~12u)) | (((v) & 4u) << 1) | (((v) & 8u) >> 1))

// LDS map (bytes) — identical to r6
#define A2_OFF   0           // 131072 : W2 A-frags, frag(kt,mt) @ (kt*8+mt)*1024 + l*16
#define A1_OFF   131072      // 4096   : [W1t|b1] A-frags, lo lanes only: fr*512 + c*16
#define Z_OFF    135168      // 16     : shared zero block (broadcast reads)
#define A3_OFF   135184      // 1536   : W3 A-frags: kt*96 + (hi*3+c)*16 (c<3)
#define SCR_OFF  136720      // 16384  : packing scratch (16 W2 rows fp32)
#define LDS_TOTAL 153104

__device__ __forceinline__ uint32_t cvtpk(float lo, float hi) {
    uint32_t r;
    asm("v_cvt_pk_bf16_f32 %0, %1, %2" : "=v"(r) : "v"(lo), "v"(hi));
    return r;
}

__global__ __launch_bounds__(NTHR, 2) void fused_kernel(
    const float* __restrict__ x,  const float* __restrict__ W1,
    const float* __restrict__ b1, const float* __restrict__ W2,
    const float* __restrict__ b2, const float* __restrict__ W3,
    const float* __restrict__ b3, float* __restrict__ out)
{
    extern __shared__ char smem[];
    uint4* frag4 = (uint4*)(smem + A2_OFF);
    float* scrf  = (float*)(smem + SCR_OFF);
    uint4* scr4  = (uint4*)(smem + SCR_OFF);

    const int tid = threadIdx.x;
    const int l   = tid & 63;
    const int hi  = l >> 5;       // k-half within frags
    const int c   = l & 31;       // batch column / A-row within tile

    // ================= one-time packing (verbatim from r6, HW-verified) =========
    {
        int fr = tid >> 6, l2 = tid & 63;
        if (l2 < 32) {
            int row = fr * 32 + l2;
            uint4 v;
            v.x = cvtpk(W1[row], W1[256 + row]);
            v.y = cvtpk(W1[512 + row], b1[row]);
            v.z = 0; v.w = 0;
            ((uint4*)(smem + A1_OFF))[fr * 32 + l2] = v;
        }
        if (tid == 511) ((uint4*)(smem + Z_OFF))[0] = make_uint4(0, 0, 0, 0);
        if (tid < 96) {
            int fr3 = tid / 6, rem = tid % 6, hi2 = rem / 3, c2 = rem % 3;
            int kb = 16 * fr3 + 8 * hi2;
            uint4 v;
            v.x = cvtpk(W3[(kb + 0) * 3 + c2], W3[(kb + 1) * 3 + c2]);
            v.y = cvtpk(W3[(kb + 2) * 3 + c2], W3[(kb + 3) * 3 + c2]);
            v.z = cvtpk(W3[(kb + 4) * 3 + c2], W3[(kb + 5) * 3 + c2]);
            v.w = cvtpk(W3[(kb + 6) * 3 + c2], W3[(kb + 7) * 3 + c2]);
            ((uint4*)(smem + A3_OFF))[fr3 * 6 + rem] = v;
        }
    }
    const uint4* gw2 = (const uint4*)W2;
    for (int kt = 0; kt < 16; ++kt) {
        __syncthreads();
        scr4[tid]       = gw2[kt * 1024 + tid];
        scr4[tid + 512] = gw2[kt * 1024 + 512 + tid];
        __syncthreads();
        int mt = tid >> 6, l2 = tid & 63, hi2 = l2 >> 5, c2 = l2 & 31;
        int col = 32 * mt + (int)SW((unsigned)c2);
        float f[8];
#pragma unroll
        for (int j = 0; j < 8; ++j) {
            int lrow = 8 * (j >> 2) + 4 * hi2 + (j & 3);
            f[j] = scrf[lrow * 256 + col];
        }
        uint4 v;
        v.x = cvtpk(f[0], f[1]); v.y = cvtpk(f[2], f[3]);
        v.z = cvtpk(f[4], f[5]); v.w = cvtpk(f[6], f[7]);
        frag4[(kt * 8 + mt) * 64 + l2] = v;
    }
    __syncthreads();   // LDS read-only from here; waves fully independent

    // ================= per-lane held constants =================
    const f32x16 Z = {0,0,0,0,0,0,0,0,0,0,0,0,0,0,0,0};
    uint32_t b2pk[8];
#pragma unroll
    for (int mt = 0; mt < 8; ++mt)
        b2pk[mt] = hi ? 0u : cvtpk(b2[32 * mt + (int)SW((unsigned)c)], 0.0f);
    union { short8 s8; uint32_t u[4]; } bB;
    bB.u[0] = hi ? 0u : 0x3F80u; bB.u[1] = 0; bB.u[2] = 0; bB.u[3] = 0;
    const short8 biasB = bB.s8;
    const float b30 = b3[0], b31 = b3[1], b32 = b3[2];

    const int a1step = hi ? 0 : 512;
    const int a1base = hi ? Z_OFF : (A1_OFF + c * 16);
    const int a3step = (c < 3) ? 96 : 0;
    const int a3base = (c < 3) ? (A3_OFF + (hi * 3 + c) * 16) : Z_OFF;

    const int gwave = blockIdx.x * 8 + (tid >> 6);

    // x staging (double-buffered): lane's rows = chunk*64 + nt*32 + c
    float xb[18], xn[18];
    {
        int r0 = gwave * 64 + c;
#pragma unroll
        for (int nt = 0; nt < 2; ++nt) {
            int row = r0 + nt * 32; row = row < NROWS ? row : NROWS - 1;
            const float* xp = x + (size_t)row * 9;
#pragma unroll
            for (int j = 0; j < 9; ++j) xb[nt * 9 + j] = xp[j];
        }
    }

    // ============ steady state: 64 rows/chunk, FOUR passes of 2 mt each ==========
    // live accumulators per pass: acc[2][2] = 64 VGPR (peak demand ~215 < 256 cap)
    for (int chunk = gwave; chunk < NCHUNK; chunk += NWAVE_TOT) {
        // prefetch next chunk's x
        {
            int nxt = chunk + NWAVE_TOT; if (nxt >= NCHUNK) nxt = chunk;
            int r0 = nxt * 64 + c;
#pragma unroll
            for (int nt = 0; nt < 2; ++nt) {
                int row = r0 + nt * 32; row = row < NROWS ? row : NROWS - 1;
                const float* xp = x + (size_t)row * 9;
#pragma unroll
                for (int j = 0; j < 9; ++j) xn[nt * 9 + j] = xp[j];
            }
        }

        // bond lengths -> layer-1 B-frags (held across passes; 8 VGPR)
        short8 qfrag[2];
#pragma unroll
        for (int nt = 0; nt < 2; ++nt) {
            const float* xp = xb + nt * 9;
            float d0 = xp[0] - xp[3], d1 = xp[1] - xp[4], d2 = xp[2] - xp[5];
            float e0 = xp[0] - xp[6], e1 = xp[1] - xp[7], e2 = xp[2] - xp[8];
            float f0 = xp[3] - xp[6], f1 = xp[4] - xp[7], f2 = xp[5] - xp[8];
            float q0 = sqrtf(fmaf(d0, d0, fmaf(d1, d1, d2 * d2)));
            float q1 = sqrtf(fmaf(e0, e0, fmaf(e1, e1, e2 * e2)));
            float q2 = sqrtf(fmaf(f0, f0, fmaf(f1, f1, f2 * f2)));
            union { short8 s8; uint32_t u[4]; } qf;
            qf.u[0] = hi ? 0u : cvtpk(q0, q1);
            qf.u[1] = hi ? 0u : cvtpk(q2, 1.0f);
            qf.u[2] = 0; qf.u[3] = 0;
            qfrag[nt] = qf.s8;
        }

        f32x16 d3[2] = {Z, Z};

#pragma unroll
        for (int P = 0; P < 4; ++P) {
            // acc init = b2 via bias-MFMA for this pass's 2 mt (global mt = 2P+m2)
            f32x16 acc[2][2];
#pragma unroll
            for (int m2 = 0; m2 < 2; ++m2) {
                union { short8 s8; uint32_t u[4]; } bA;
                bA.u[0] = b2pk[2 * P + m2]; bA.u[1] = 0; bA.u[2] = 0; bA.u[3] = 0;
#pragma unroll
                for (int nt = 0; nt < 2; ++nt)
                    acc[m2][nt] = __builtin_amdgcn_mfma_f32_32x32x16_bf16(bA.s8, biasB, Z, 0, 0, 0);
            }
            // layer-1 (recomputed per pass) -> pack -> layer-2 for this mt pair
#pragma unroll
            for (int tau = 0; tau < 8; ++tau) {
                short8 a1 = *(const short8*)(smem + a1base + tau * a1step);
                f32x16 d1v[2];
#pragma unroll
                for (int nt = 0; nt < 2; ++nt)
                    d1v[nt] = __builtin_amdgcn_mfma_f32_32x32x16_bf16(a1, qfrag[nt], Z, 0, 0, 0);
#pragma unroll
                for (int p = 0; p < 2; ++p) {
                    const int kt = 2 * tau + p;
                    short8 bfr[2];
#pragma unroll
                    for (int nt = 0; nt < 2; ++nt) {
                        union { short8 s8; uint32_t u[4]; } pk;
#pragma unroll
                        for (int w = 0; w < 4; ++w)
                            pk.u[w] = cvtpk(fmaxf(d1v[nt][8 * p + 2 * w], 0.0f),
                                            fmaxf(d1v[nt][8 * p + 2 * w + 1], 0.0f));
                        bfr[nt] = pk.s8;
                    }
#pragma unroll
                    for (int m2 = 0; m2 < 2; ++m2) {
                        short8 a2 = *(const short8*)(smem +
                                     (size_t)((kt * 8 + 2 * P + m2) * 1024) + l * 16);
#pragma unroll
                        for (int nt = 0; nt < 2; ++nt)
                            acc[m2][nt] = __builtin_amdgcn_mfma_f32_32x32x16_bf16(a2, bfr[nt], acc[m2][nt], 0, 0, 0);
                    }
                }
            }
            // layer-3 partial for this pass's kt3 range (global mt = kt3>>1 = 2P+m2)
#pragma unroll
            for (int i = 0; i < 4; ++i) {
                const int kt3 = 4 * P + i;
                const int m2 = i >> 1, p = i & 1;
                short8 a3 = *(const short8*)(smem + a3base + kt3 * a3step);
#pragma unroll
                for (int nt = 0; nt < 2; ++nt) {
                    union { short8 s8; uint32_t u[4]; } pk;
#pragma unroll
                    for (int w = 0; w < 4; ++w)
                        pk.u[w] = cvtpk(fmaxf(acc[m2][nt][8 * p + 2 * w], 0.0f),
                                        fmaxf(acc[m2][nt][8 * p + 2 * w + 1], 0.0f));
                    d3[nt] = __builtin_amdgcn_mfma_f32_32x32x16_bf16(a3, pk.s8, d3[nt], 0, 0, 0);
                }
            }
        }

        // eigen + store: lo lanes hold d3 regs 0,1,2 = (w00,w11,w01) for batch col c
        if (hi == 0) {
#pragma unroll
            for (int nt = 0; nt < 2; ++nt) {
                int row = chunk * 64 + nt * 32 + c;
                if (row < NROWS) {
                    float w0 = d3[nt][0] + b30, w1v = d3[nt][1] + b31, wc = d3[nt][2] + b32;
                    float mm = 0.5f * (w0 + w1v), dd = 0.5f * (w0 - w1v);
                    float rad = sqrtf(fmaf(dd, dd, wc * wc));
                    *(float2*)(out + (size_t)row * 2) = make_float2(mm - rad, mm + rad);
                }
            }
        }

        // rotate prefetched x
#pragma unroll
        for (int j = 0; j < 18; ++j) xb[j] = xn[j];
    }
}

extern "C" void kernel_launch(void* const* d_in, const int* in_sizes, int n_in,
                              void* d_out, int out_size, void* d_ws, size_t ws_size,
                              hipStream_t stream) {
    const float* x  = (const float*)d_in[0];
    const float* W1 = (const float*)d_in[1];
    const float* b1 = (const float*)d_in[2];
    const float* W2 = (const float*)d_in[3];
    const float* b2 = (const float*)d_in[4];
    const float* W3 = (const float*)d_in[5];
    const float* b3 = (const float*)d_in[6];
    float* out = (float*)d_out;

    (void)d_ws; (void)ws_size;

    (void)hipFuncSetAttribute((const void*)fused_kernel,
                              hipFuncAttributeMaxDynamicSharedMemorySize, LDS_TOTAL);

    fused_kernel<<<NBLK, NTHR, LDS_TOTAL, stream>>>(x, W1, b1, W2, b2, W3, b3, out);
}